// Round 7
// baseline (104.957 us; speedup 1.0000x reference)
//
#include <hip/hip_runtime.h>
#include <math.h>

#define NC 15
#define TOPKK 15
#define BG_F 15.0f
#define MAXC 256
#define CSTRIDE 32  // ints per counter slot -> 128 B, one cache line each

// All-register rotated-box IoU. Mirrors pairwise_riou exactly:
// fixed candidate slots 0..15 = edge intersections (e1*4+e2),
// 16..19 = corners of box1, 20..23 = corners of box2; a validity BITMASK
// replaces boolean arrays; stable repeated min-extraction over angles
// (strict <, lowest slot first) replicates stable jnp.argsort order.
// No runtime array indexing anywhere -> no scratch.
__device__ __forceinline__ float obb_iou_reg(
    float cx1, float cy1, float w1, float h1, float a1,
    float cx2, float cy2, float w2, float h2, float a2) {
  const float dxs[4] = {0.5f, 0.5f, -0.5f, -0.5f};
  const float dys[4] = {-0.5f, 0.5f, 0.5f, -0.5f};
  float c1 = cosf(a1), s1 = sinf(a1), c2 = cosf(a2), s2 = sinf(a2);
  float ax[4], ay[4], bx[4], by[4];
#pragma unroll
  for (int k = 0; k < 4; k++) {
    float dx = dxs[k] * w1, dy = dys[k] * h1;
    ax[k] = cx1 + dx * c1 - dy * s1;
    ay[k] = cy1 + dx * s1 + dy * c1;
    dx = dxs[k] * w2; dy = dys[k] * h2;
    bx[k] = cx2 + dx * c2 - dy * s2;
    by[k] = cy2 + dx * s2 + dy * c2;
  }
  float qx[24], qy[24];
#pragma unroll
  for (int k = 0; k < 24; k++) { qx[k] = 0.f; qy[k] = 0.f; }
  unsigned valid = 0u;
#pragma unroll
  for (int e1 = 0; e1 < 4; e1++) {
    float d1x = ax[(e1 + 1) & 3] - ax[e1], d1y = ay[(e1 + 1) & 3] - ay[e1];
#pragma unroll
    for (int e2 = 0; e2 < 4; e2++) {
      float d2x = bx[(e2 + 1) & 3] - bx[e2], d2y = by[(e2 + 1) & 3] - by[e2];
      float den = d1x * d2y - d1y * d2x;
      float qpx = bx[e2] - ax[e1], qpy = by[e2] - ay[e1];
      float t = (qpx * d2y - qpy * d2x) / den;
      float u = (qpx * d1y - qpy * d1x) / den;
      bool ok = (fabsf(den) > 1e-10f) &&
                (t >= 0.f) && (t <= 1.f) && (u >= 0.f) && (u <= 1.f);
      if (ok) {
        qx[e1 * 4 + e2] = ax[e1] + t * d1x;
        qy[e1 * 4 + e2] = ay[e1] + t * d1y;
        valid |= (1u << (e1 * 4 + e2));
      }
    }
  }
  const float eps = 1e-6f;
#pragma unroll
  for (int k = 0; k < 4; k++) {
    float rx = ax[k] - cx2, ry = ay[k] - cy2;
    float x = rx * c2 + ry * s2, y = -rx * s2 + ry * c2;
    if (fabsf(x) <= w2 * 0.5f + eps && fabsf(y) <= h2 * 0.5f + eps) {
      qx[16 + k] = ax[k]; qy[16 + k] = ay[k];
      valid |= (1u << (16 + k));
    }
  }
#pragma unroll
  for (int k = 0; k < 4; k++) {
    float rx = bx[k] - cx1, ry = by[k] - cy1;
    float x = rx * c1 + ry * s1, y = -rx * s1 + ry * c1;
    if (fabsf(x) <= w1 * 0.5f + eps && fabsf(y) <= h1 * 0.5f + eps) {
      qx[20 + k] = bx[k]; qy[20 + k] = by[k];
      valid |= (1u << (20 + k));
    }
  }
  int cnt = __popc(valid);
  float inter = 0.f;
  if (cnt > 0) {
    float sx = 0.f, sy = 0.f;
#pragma unroll
    for (int k = 0; k < 24; k++) {
      bool v = (valid >> k) & 1u;
      sx += v ? qx[k] : 0.f;
      sy += v ? qy[k] : 0.f;
    }
    float ccx = sx / (float)cnt, ccy = sy / (float)cnt;
    float ang[24];
#pragma unroll
    for (int k = 0; k < 24; k++) {
      float a = atan2f(qy[k] - ccy, qx[k] - ccx);
      ang[k] = ((valid >> k) & 1u) ? a : 1e9f;
    }
    unsigned used = ~valid;  // invalid slots pre-consumed
    float area2 = 0.f;
    float prevx = 0.f, prevy = 0.f, firstx = 0.f, firsty = 0.f;
    for (int s = 0; s < cnt; s++) {
      float ba = 1e30f, bxv = 0.f, byv = 0.f;
      int bk = 0;
#pragma unroll
      for (int k = 0; k < 24; k++) {
        bool avail = !((used >> k) & 1u);
        bool better = avail && (ang[k] < ba);
        if (better) { ba = ang[k]; bxv = qx[k]; byv = qy[k]; bk = k; }
      }
      used |= (1u << bk);
      float vx = bxv - ccx, vy = byv - ccy;
      if (s == 0) { firstx = vx; firsty = vy; }
      else { area2 += prevx * vy - prevy * vx; }
      prevx = vx; prevy = vy;
    }
    area2 += prevx * firsty - prevy * firstx;  // closing edge
    inter = 0.5f * fabsf(area2);
  }
  float areaA = w1 * h1, areaB = w2 * h2;
  return inter / fmaxf(areaA + areaB - inter, 1e-8f);
}

// Wide scan: blk = chunk*G + g. Per-block centerness best -> plain store to
// blk_cent[blk]. Candidate append: ballot -> LDS wave counts -> ONE
// atomicAdd per block (only if block has any valid), counters padded to
// 128 B each -> no same-line serialization. g==0 blocks zero point_key.
__global__ void k_scan(const float* __restrict__ pts,
                       const float* __restrict__ rr,
                       const float* __restrict__ spp,
                       const float* __restrict__ gtb,
                       int* __restrict__ cand_cnt,
                       int* __restrict__ cand_i,
                       unsigned long long* __restrict__ blk_cent,
                       unsigned long long* __restrict__ point_key,
                       int N, int G) {
  int blk = blockIdx.x;
  int g = blk % G, chunk = blk / G;
  int i = chunk * 256 + threadIdx.x;
  if (g == 0 && i < N) point_key[i] = 0ull;
  float gx = gtb[g * 5 + 0], gy = gtb[g * 5 + 1];
  float gw = gtb[g * 5 + 2], gh = gtb[g * 5 + 3], ga = gtb[g * 5 + 4];
  float cg = cosf(ga), sg = sinf(ga);
  float inv_gw = 2.f / gw, inv_gh = 2.f / gh;
  float hw = gw * 0.5f, hh = gh * 0.5f;

  unsigned long long key = 0ull;
  bool valid = false;
  if (i < N) {
    float2 p = ((const float2*)pts)[i];
    float px = p.x - gx, py = p.y - gy;
    float ox = px * cg + py * sg, oy = -px * sg + py * cg;
    float nx = ox * inv_gw, ny = oy * inv_gh;
    float ctn = fmaxf(1.f - sqrtf((nx * nx + ny * ny + 1e-8f) * 0.5f), 0.f);
    key = ((unsigned long long)__float_as_uint(ctn) << 32) |
          (unsigned long long)(0xFFFFFFFFu - (unsigned)i);
    float l = hw + ox, tt = hh + oy, r = hw - ox, b = hh - oy;
    float minb = fminf(fminf(l, tt), fminf(r, b));
    float maxb = fmaxf(fmaxf(l, tt), fmaxf(r, b));
    float cr = 1.5f * spp[i];
    float2 rv = ((const float2*)rr)[i];
    valid = (minb > 0.f) && (fabsf(ox) < cr) && (fabsf(oy) < cr) &&
            (maxb >= rv.x) && (maxb <= rv.y);
  }
  int lane = threadIdx.x & 63, wid = threadIdx.x >> 6;
  // block reduce centerness key (max ctn, min i via ~i): wave shfl + LDS
  unsigned long long best = key;
#pragma unroll
  for (int o = 32; o > 0; o >>= 1) {
    unsigned long long other = __shfl_xor(best, o, 64);
    if (other > best) best = other;
  }
  __shared__ unsigned long long swin[4];
  __shared__ int s_wcnt[4];
  __shared__ int s_base;
  unsigned long long ball = __ballot(valid);
  if (lane == 0) {
    swin[wid] = best;
    s_wcnt[wid] = __popcll(ball);
  }
  __syncthreads();
  if (threadIdx.x == 0) {
    unsigned long long m = swin[0];
#pragma unroll
    for (int q = 1; q < 4; q++) if (swin[q] > m) m = swin[q];
    blk_cent[blk] = m;
    int tot = s_wcnt[0] + s_wcnt[1] + s_wcnt[2] + s_wcnt[3];
    s_base = (tot > 0) ? atomicAdd(&cand_cnt[g * CSTRIDE], tot) : 0;
  }
  __syncthreads();
  if (valid) {
    int woff = 0;
    for (int q = 0; q < wid; q++) woff += s_wcnt[q];
    int slot = s_base + woff + __popcll(ball & ((1ull << lane) - 1ull));
    if (slot < MAXC) cand_i[g * MAXC + slot] = i;
  }
}

// Wide heavy phase: block = g*4+q, thread = candidate slot q*64+tid.
// 128 blocks x 64 threads -> 4x CU coverage of the serial IoU chain.
__global__ void k_heavy(const float* __restrict__ pts,
                        const float* __restrict__ spp,
                        const float* __restrict__ gtb,
                        const int* __restrict__ gtl,
                        const float* __restrict__ preds,
                        const float* __restrict__ probs,
                        const int* __restrict__ cand_cnt,
                        const int* __restrict__ cand_i,
                        unsigned long long* __restrict__ cand_key,
                        int G) {
  int b = blockIdx.x;
  int g = b >> 2, q = b & 3;
  int slot = q * 64 + threadIdx.x;
  int cnt = cand_cnt[g * CSTRIDE];
  if (cnt > MAXC) cnt = MAXC;
  if (slot >= cnt) return;
  int i = cand_i[g * MAXC + slot];
  float gx = gtb[g * 5 + 0], gy = gtb[g * 5 + 1];
  float gw = gtb[g * 5 + 2], gh = gtb[g * 5 + 3], ga = gtb[g * 5 + 4];
  float cg = cosf(ga), sg = sinf(ga);
  float ptx = pts[i * 2 + 0], pty = pts[i * 2 + 1];
  float px = ptx - gx, py = pty - gy;
  float ox = px * cg + py * sg, oy = -px * sg + py * cg;
  float nx = 2.f * ox / gw, ny = 2.f * oy / gh;
  float ctn = fmaxf(1.f - sqrtf((nx * nx + ny * ny + 1e-8f) * 0.5f), 0.f);

  // softmax prob of this gt's label (jax.nn.softmax with max subtraction)
  float pv[NC];
  float m = -1e30f;
#pragma unroll
  for (int k = 0; k < NC; k++) { pv[k] = probs[i * NC + k]; m = fmaxf(m, pv[k]); }
  float ss = 0.f;
#pragma unroll
  for (int k = 0; k < NC; k++) { pv[k] = expf(pv[k] - m); ss += pv[k]; }
  float prob = pv[gtl[g]] / ss;

  // decode det box (mirrors _decode with stride-scaled preds)
  float st = spp[i];
  float d0 = preds[i * 5 + 0] * st, d1 = preds[i * 5 + 1] * st;
  float d2 = preds[i * 5 + 2] * st, d3 = preds[i * 5 + 3] * st;
  float angp = preds[i * 5 + 4];
  float c = cosf(angp), s = sinf(angp);
  float w = d0 + d2, h = d1 + d3;
  float otx = (d2 - d0) * 0.5f, oty = (d3 - d1) * 0.5f;
  float dox = c * otx - s * oty, doy = s * otx + c * oty;
  const float PI = 3.14159265358979323846f;
  float a = fmodf(angp + PI * 0.5f, PI);
  if (a < 0.f) a += PI;
  a -= PI * 0.5f;

  float iou = obb_iou_reg(ptx + dox, pty + doy, w, h, a, gx, gy, gw, gh, ga);
  float cval = 0.2f * ctn + 0.2f * iou + 0.6f * prob;
  cand_key[g * MAXC + slot] =
      ((unsigned long long)__float_as_uint(cval) << 32) |
      (unsigned long long)(0xFFFFFFFFu - (unsigned)i);
}

// One block per gt (cheap now): (1) reduce blk_cent over chunks ->
// cent_key[g]; (2) top-15 block argmax rounds over cand_key, exact
// lax.top_k tie rule (value desc, index asc); winners atomicMax the
// per-point area key (area_bits<<32)|(G-1-g) -> max area, min g on ties.
__global__ void k_top(const float* __restrict__ gtb,
                      const int* __restrict__ cand_cnt,
                      const unsigned long long* __restrict__ cand_key,
                      const unsigned long long* __restrict__ blk_cent,
                      unsigned long long* __restrict__ cent_key,
                      unsigned long long* __restrict__ point_key,
                      int G, int CH) {
  int g = blockIdx.x;
  int tid = threadIdx.x;
  int lane = tid & 63, wid = tid >> 6;
  __shared__ unsigned long long swin[4];

  // reduce per-chunk centerness keys
  unsigned long long best = 0ull;
  for (int c = tid; c < CH; c += 256) {
    unsigned long long e = blk_cent[(size_t)c * G + g];
    if (e > best) best = e;
  }
#pragma unroll
  for (int o = 32; o > 0; o >>= 1) {
    unsigned long long other = __shfl_xor(best, o, 64);
    if (other > best) best = other;
  }
  if (lane == 0) swin[wid] = best;
  __syncthreads();
  if (tid == 0) {
    unsigned long long m = swin[0];
#pragma unroll
    for (int q = 1; q < 4; q++) if (swin[q] > m) m = swin[q];
    cent_key[g] = m;
  }
  __syncthreads();

  int cnt = cand_cnt[g * CSTRIDE];
  if (cnt > MAXC) cnt = MAXC;
  unsigned long long key = (tid < cnt) ? cand_key[g * MAXC + tid] : 0ull;

  float area = gtb[g * 5 + 2] * gtb[g * 5 + 3];
  unsigned long long area_key =
      (((unsigned long long)__float_as_uint(area)) << 32) |
      (unsigned long long)(unsigned)(G - 1 - g);
  int rounds = cnt < TOPKK ? cnt : TOPKK;
  for (int r = 0; r < rounds; r++) {
    unsigned long long k2 = key;
#pragma unroll
    for (int o = 32; o > 0; o >>= 1) {
      unsigned long long other = __shfl_xor(k2, o, 64);
      if (other > k2) k2 = other;
    }
    if (lane == 0) swin[wid] = k2;
    __syncthreads();
    unsigned long long w = swin[0];
#pragma unroll
    for (int q = 1; q < 4; q++) if (swin[q] > w) w = swin[q];
    __syncthreads();
    if (w == 0ull) break;
    if (key == w) key = 0ull;  // unique owner (i unique per gt) consumes
    if (tid == 0) {
      unsigned iwin = 0xFFFFFFFFu - (unsigned)(w & 0xFFFFFFFFull);
      atomicMax(&point_key[iwin], area_key);
    }
  }
}

// Per point: resolve key -> (ind, label), count matches, write bt/at.
__global__ void k_assign(const unsigned long long* __restrict__ point_key,
                         const float* __restrict__ pts,
                         const float* __restrict__ spp,
                         const float* __restrict__ gtb,
                         const int* __restrict__ gtl,
                         int* __restrict__ counts,
                         float* __restrict__ out_labels,
                         float* __restrict__ out_bt,
                         float* __restrict__ out_at,
                         int N, int G) {
  int i = blockIdx.x * blockDim.x + threadIdx.x;
  if (i >= N) return;
  unsigned long long key = point_key[i];
  int g = 0;
  if (key != 0ull) {
    g = (G - 1) - (int)(key & 0xFFFFFFFFull);
    out_labels[i] = (float)gtl[g];
    atomicAdd(&counts[g * CSTRIDE], 1);
  } else {
    out_labels[i] = BG_F;  // argmax of all-zero row -> ind 0, label BG
  }
  float gx = gtb[g * 5 + 0], gy = gtb[g * 5 + 1];
  float gw = gtb[g * 5 + 2], gh = gtb[g * 5 + 3], ga = gtb[g * 5 + 4];
  float cg = cosf(ga), sg = sinf(ga);
  float px = pts[i * 2 + 0] - gx, py = pts[i * 2 + 1] - gy;
  float ox = px * cg + py * sg, oy = -px * sg + py * cg;
  float st = spp[i];
  out_bt[i * 4 + 0] = (gw * 0.5f + ox) / st;
  out_bt[i * 4 + 1] = (gh * 0.5f + oy) / st;
  out_bt[i * 4 + 2] = (gw * 0.5f - ox) / st;
  out_bt[i * 4 + 3] = (gh * 0.5f - oy) / st;
  out_at[i] = ga;
}

// One wave, lane = gt. Unmatched gts claim their anchor point. Exact
// last-writer-wins (ascending g) on duplicate anchors via shfl resolution:
// lane g yields if any higher unmatched lane has the same anchor.
__global__ void k_fix(const int* __restrict__ counts,
                      const unsigned long long* __restrict__ cent_key,
                      const float* __restrict__ pts,
                      const float* __restrict__ spp,
                      const float* __restrict__ gtb,
                      const int* __restrict__ gtl,
                      float* __restrict__ out_labels,
                      float* __restrict__ out_bt,
                      float* __restrict__ out_at,
                      int G) {
  int g = threadIdx.x;  // blockDim = 64, G <= 64
  bool active = (g < G) && (counts[g * CSTRIDE] == 0);
  unsigned anchor = 0xFFFFFFFFu;
  if (active) anchor = 0xFFFFFFFFu - (unsigned)(cent_key[g] & 0xFFFFFFFFull);
  unsigned long long act = __ballot(active);
  bool winner = active;
  for (int o = 0; o < 64; o++) {
    unsigned oa = __shfl(anchor, o, 64);
    if (active && o > g && ((act >> o) & 1ull) && oa == anchor) winner = false;
  }
  if (winner) {
    unsigned i = anchor;
    out_labels[i] = (float)gtl[g];
    float gx = gtb[g * 5 + 0], gy = gtb[g * 5 + 1];
    float gw = gtb[g * 5 + 2], gh = gtb[g * 5 + 3], ga = gtb[g * 5 + 4];
    float cg = cosf(ga), sg = sinf(ga);
    float px = pts[i * 2 + 0] - gx, py = pts[i * 2 + 1] - gy;
    float ox = px * cg + py * sg, oy = -px * sg + py * cg;
    float st = spp[i];
    out_bt[i * 4 + 0] = (gw * 0.5f + ox) / st;
    out_bt[i * 4 + 1] = (gh * 0.5f + oy) / st;
    out_bt[i * 4 + 2] = (gw * 0.5f - ox) / st;
    out_bt[i * 4 + 3] = (gh * 0.5f - oy) / st;
    out_at[i] = ga;
  }
}

extern "C" void kernel_launch(void* const* d_in, const int* in_sizes, int n_in,
                              void* d_out, int out_size, void* d_ws, size_t ws_size,
                              hipStream_t stream) {
  const float* pts   = (const float*)d_in[0];
  const float* rr    = (const float*)d_in[1];
  const float* spp   = (const float*)d_in[2];
  const float* gtb   = (const float*)d_in[3];
  const int*   gtl   = (const int*)d_in[4];
  const float* preds = (const float*)d_in[5];
  const float* probs = (const float*)d_in[6];
  int N = in_sizes[0] / 2;
  int G = in_sizes[3] / 5;
  int CH = (N + 255) / 256;  // point chunks

  float* out = (float*)d_out;
  float* out_labels = out;                   // N
  float* out_bt     = out + N;               // N*4
  float* out_at     = out + 5 * (size_t)N;   // N

  // ws: [cand_cnt G*32 | counts G*32] (memset 0, padded counters)
  //     [cent_key G u64][point_key N u64 (zeroed by k_scan g==0)]
  //     [blk_cent CH*G u64][cand_i G*MAXC i32][cand_key G*MAXC u64]
  int* cand_cnt = (int*)d_ws;                                     // G*32
  int* counts   = cand_cnt + G * CSTRIDE;                         // G*32
  unsigned long long* cent_key =
      (unsigned long long*)(counts + G * CSTRIDE);                // G
  unsigned long long* point_key = cent_key + G;                   // N
  unsigned long long* blk_cent  = point_key + N;                  // CH*G
  int* cand_i = (int*)(blk_cent + (size_t)CH * G);                // G*MAXC
  unsigned long long* cand_key =
      (unsigned long long*)(cand_i + (size_t)G * MAXC);           // G*MAXC

  hipMemsetAsync(d_ws, 0, (size_t)G * CSTRIDE * 4 * 2, stream);

  const int thr = 256;
  hipLaunchKernelGGL(k_scan, dim3(CH * G), dim3(thr), 0, stream,
                     pts, rr, spp, gtb, cand_cnt, cand_i,
                     blk_cent, point_key, N, G);
  hipLaunchKernelGGL(k_heavy, dim3(G * 4), dim3(64), 0, stream,
                     pts, spp, gtb, gtl, preds, probs,
                     cand_cnt, cand_i, cand_key, G);
  hipLaunchKernelGGL(k_top, dim3(G), dim3(thr), 0, stream,
                     gtb, cand_cnt, cand_key, blk_cent,
                     cent_key, point_key, G, CH);
  hipLaunchKernelGGL(k_assign, dim3((N + thr - 1) / thr), dim3(thr), 0, stream,
                     point_key, pts, spp, gtb, gtl, counts,
                     out_labels, out_bt, out_at, N, G);
  hipLaunchKernelGGL(k_fix, dim3(1), dim3(64), 0, stream,
                     counts, cent_key, pts, spp, gtb, gtl,
                     out_labels, out_bt, out_at, G);
}